// Round 6
// baseline (144.813 us; speedup 1.0000x reference)
//
#include <hip/hip_runtime.h>
#include <hip/hip_bf16.h>
#include <math.h>

// Problem dims
#define TOK   8192
#define KDIM  8192
#define F_DIM 64
#define U_DIM 128
#define N3    384

// GEMM tiling
#define BM    64
#define BK    64
#define KSPL  4
#define KRANGE (KDIM / KSPL)     // 2048
#define NST   (KRANGE / BK)      // 32
#define NF    (KRANGE / U_DIM)   // 16

typedef __bf16 bf16x8 __attribute__((ext_vector_type(8)));
typedef float  f32x4  __attribute__((ext_vector_type(4)));

// tanh-approx GELU: z - z/(1 + 2^(z*(2.30234 + 0.102955 z^2))), |err| < ~1e-3
__device__ __forceinline__ float gelu_fast(float z) {
    float t = z * z;
    float s = fmaf(0.1029551f, t, 2.3023457f);
    float e = __builtin_amdgcn_exp2f(z * s);
    float r = __builtin_amdgcn_rcpf(e + 1.0f);   // +inf -> 0
    return fmaf(-z, r, z);
}

__device__ __forceinline__ float bflo(unsigned u) { u <<= 16; return __builtin_bit_cast(float, u); }
__device__ __forceinline__ float bfhi(unsigned u) { u &= 0xffff0000u; return __builtin_bit_cast(float, u); }

// ---------------------------------------------------------------------------
// Kernel 1: pack W[k][n] f32 (3 mats) -> Bp[k/32][n(384)][k%32] bf16,
// plus (block 768) lin_w -> bf16-pair-packed linp[128][64].
// ---------------------------------------------------------------------------
__global__ __launch_bounds__(256) void vsn_prep6(
    const float* __restrict__ elu_w,
    const float* __restrict__ gate_w,
    const float* __restrict__ proj_w,
    const float* __restrict__ lin_w,
    __bf16* __restrict__ Bp,
    unsigned* __restrict__ linp)
{
    const int t = threadIdx.x;
    if (blockIdx.x == 3 * (KDIM / 32)) {
#pragma unroll
        for (int i = 0; i < 32; ++i) {
            int idx = i * 256 + t;            // 0..8191
            int v = idx >> 6, l = idx & 63;
            __bf16 ba = (__bf16)lin_w[v * U_DIM + 2 * l];
            __bf16 bb = (__bf16)lin_w[v * U_DIM + 2 * l + 1];
            unsigned pa = (unsigned)__builtin_bit_cast(unsigned short, ba);
            unsigned pb = (unsigned)__builtin_bit_cast(unsigned short, bb);
            linp[idx] = pa | (pb << 16);
        }
        return;
    }
    __shared__ float tile[32][U_DIM + 1];
    const int mat = blockIdx.x / (KDIM / 32);
    const int kb  = blockIdx.x % (KDIM / 32);
    const float* W = (mat == 0) ? elu_w : (mat == 1 ? gate_w : proj_w);

#pragma unroll
    for (int i = 0; i < 16; ++i) {
        int idx = i * 256 + t;
        int r = idx >> 7, c = idx & 127;
        tile[r][c] = W[(size_t)(kb * 32 + r) * U_DIM + c];
    }
    __syncthreads();
#pragma unroll
    for (int i = 0; i < 16; ++i) {
        int idx = i * 256 + t;
        int c = idx >> 5, r = idx & 31;
        Bp[((size_t)kb * N3 + mat * U_DIM + c) * 32 + r] = (__bf16)tile[r][c];
    }
}

// ---------------------------------------------------------------------------
// Kernel 2: fused gelu-feat + 3-way GEMM — BARRIER-FREE inner loop.
// grid = (KSPL=4, TOK/BM=128) = 512 WGs, 256 thr (4 waves; wave = 96 cols,
// acc[4][6] = all 64 rows). Each wave computes its own A-fragments (gelu)
// in REGISTERS from x_lds/fw_lds/fb_lds (staged once) — no cross-wave
// sharing, no inner-loop __syncthreads, waves free-run as independent
// streams (VALU of one wave overlaps MFMA/L2 of the other).
// XCD id%8 of (bx + 4*by) in {s, s+4}: one k-split per XCD (B L2-resident).
// ---------------------------------------------------------------------------
__global__ __launch_bounds__(256, 2) void vsn_gemm6(
    const float* __restrict__ x,
    const float* __restrict__ fw,
    const float* __restrict__ fb,
    const __bf16* __restrict__ Bp,
    __bf16* __restrict__ Hp)
{
    __shared__ float  x_lds[BM][NF + 1];      // 64x17 f32 = 4.3 KB
    __shared__ __bf16 fw_lds[KRANGE];         // 4 KB
    __shared__ __bf16 fb_lds[KRANGE];         // 4 KB

    const int t    = threadIdx.x;
    const int wave = t >> 6;
    const int lane = t & 63;
    const int s     = blockIdx.x;
    const int tok0  = blockIdx.y * BM;
    const int kbase = s * KRANGE;
    const int wn = wave;                      // 96-col band
    const int lr  = lane & 15;
    const int lk8 = (lane >> 4) * 8;

    // ---- stage x (64x16), fw/fb (2048 each); once, then one barrier
#pragma unroll
    for (int i = 0; i < (BM * NF) / 256; ++i) {
        int idx = i * 256 + t;
        int r = idx >> 4, c = idx & 15;
        x_lds[r][c] = x[(size_t)(tok0 + r) * F_DIM + (kbase >> 7) + c];
    }
#pragma unroll
    for (int i = 0; i < KRANGE / 256; ++i) {
        int k = i * 256 + t;
        fw_lds[k] = (__bf16)fw[kbase + k];
        fb_lds[k] = (__bf16)fb[kbase + k];
    }

    f32x4 acc[4][6];
#pragma unroll
    for (int i = 0; i < 4; ++i)
#pragma unroll
        for (int j = 0; j < 6; ++j)
            acc[i][j] = (f32x4){0.f, 0.f, 0.f, 0.f};

    const __bf16* bb = Bp + (size_t)(kbase >> 5) * (N3 * 32)
                          + (wn * 96 + lr) * 32 + lk8;

    __syncthreads();               // the ONLY workgroup barrier

    for (int st = 0; st < NST; ++st) {
        const int k0 = st * BK;
        const int fcol = st >> 1;  // x feature column (local), same all ksi

        // issue all 12 B loads first (L2; latency hidden under gelu VALU)
        bf16x8 bf[2][6];
#pragma unroll
        for (int ksi = 0; ksi < 2; ++ksi) {
            const __bf16* p = bb + (size_t)(st * 2 + ksi) * (N3 * 32);
#pragma unroll
            for (int j = 0; j < 6; ++j)
                bf[ksi][j] = *(const bf16x8*)(p + j * 512);
        }

        // per-row x scalars (broadcast ds_reads)
        float xs[4];
#pragma unroll
        for (int i = 0; i < 4; ++i)
            xs[i] = x_lds[i * 16 + lr][fcol];

        // A-fragments in registers: af[ksi][i][j] =
        //   gelu(xs[i] * fw[k0+ksi*32+lk8+j] + fb[...]) — same values the
        //   LDS path produced (row = i*16+lr, k-off = (lane>>4)*8 + j)
#pragma unroll
        for (int ksi = 0; ksi < 2; ++ksi) {
            bf16x8 wv = *(const bf16x8*)&fw_lds[k0 + ksi * 32 + lk8];
            bf16x8 bv = *(const bf16x8*)&fb_lds[k0 + ksi * 32 + lk8];
            bf16x8 af[4];
#pragma unroll
            for (int i = 0; i < 4; ++i) {
#pragma unroll
                for (int j = 0; j < 8; ++j) {
                    float z = fmaf(xs[i], (float)wv[j], (float)bv[j]);
                    af[i][j] = (__bf16)gelu_fast(z);
                }
            }
#pragma unroll
            for (int i = 0; i < 4; ++i)
#pragma unroll
                for (int j = 0; j < 6; ++j)
                    acc[i][j] = __builtin_amdgcn_mfma_f32_16x16x32_bf16(
                        af[i], bf[ksi][j], acc[i][j], 0, 0, 0);
        }
    }

    // ---- write bf16 partials (C/D: col=lane&15, row=(lane>>4)*4+r)
    __bf16* Hs = Hp + (size_t)s * ((size_t)TOK * N3);
    const int r0 = (lane >> 4) * 4;
#pragma unroll
    for (int i = 0; i < 4; ++i)
#pragma unroll
        for (int j = 0; j < 6; ++j)
#pragma unroll
            for (int r = 0; r < 4; ++r)
                Hs[(size_t)(tok0 + i * 16 + r0 + r) * N3 + wn * 96 + j * 16 + lr]
                    = (__bf16)acc[i][j][r];
}

// ---------------------------------------------------------------------------
// Kernel 3: epilogue. grid = TOK/16 = 512 WGs x 256 thr; wave = 4 tokens.
// Lane l owns feature pair (2l, 2l+1); shfl-broadcast matmuls over 4 tokens.
// ---------------------------------------------------------------------------
__global__ __launch_bounds__(256) void vsn_epi6(
    const float* __restrict__ x,
    const __bf16* __restrict__ Hp,
    const unsigned* __restrict__ linp,
    const float* __restrict__ elu_b,
    const float* __restrict__ lin_b,
    const float* __restrict__ gate_b,
    const float* __restrict__ ln_g,
    const float* __restrict__ ln_b,
    const float* __restrict__ sm_w,
    const float* __restrict__ sm_b,
    float* __restrict__ out)
{
    __shared__ unsigned lin_lds[U_DIM * 64];     // 32 KB (bf16 pairs)
    __shared__ float    smw_lds[U_DIM * F_DIM];  // 32 KB
    const int t = threadIdx.x, wave = t >> 6, lane = t & 63;
    const int tokb = blockIdx.x * 16 + wave * 4;

    {
        const uint4* l4 = (const uint4*)linp;
        uint4* d4 = (uint4*)lin_lds;
#pragma unroll
        for (int i = 0; i < 8; ++i) d4[i * 256 + t] = l4[i * 256 + t];
        const f32x4* s4 = (const f32x4*)sm_w;
        f32x4* m4 = (f32x4*)smw_lds;
#pragma unroll
        for (int i = 0; i < 8; ++i) m4[i * 256 + t] = s4[i * 256 + t];
    }
    __syncthreads();

    const float2 eb  = *(const float2*)&elu_b[2 * lane];
    const float2 gb  = *(const float2*)&gate_b[2 * lane];
    const float2 lb  = *(const float2*)&lin_b[2 * lane];
    const float2 lg2 = *(const float2*)&ln_g[2 * lane];
    const float2 lnb = *(const float2*)&ln_b[2 * lane];
    const float  smb = sm_b[lane];

    float h1a[4], h1b[4], ga[4], gbt[4], pa[4], pb[4];
#pragma unroll
    for (int tk = 0; tk < 4; ++tk) {
        const unsigned short* base =
            (const unsigned short*)Hp + (size_t)(tokb + tk) * N3;
        float a0 = 0.f, a1 = 0.f, g0 = 0.f, g1 = 0.f, p0 = 0.f, p1 = 0.f;
#pragma unroll
        for (int s = 0; s < KSPL; ++s) {
            const unsigned short* bs = base + (size_t)s * TOK * N3;
            unsigned ua = *(const unsigned*)(bs + 2 * lane);
            unsigned ug = *(const unsigned*)(bs + 128 + 2 * lane);
            unsigned up = *(const unsigned*)(bs + 256 + 2 * lane);
            a0 += bflo(ua); a1 += bfhi(ua);
            g0 += bflo(ug); g1 += bfhi(ug);
            p0 += bflo(up); p1 += bfhi(up);
        }
        float e0 = a0 + eb.x, e1 = a1 + eb.y;
        h1a[tk] = (e0 > 0.f) ? e0 : expm1f(e0);
        h1b[tk] = (e1 > 0.f) ? e1 : expm1f(e1);
        ga[tk]  = 1.f / (1.f + __expf(-(g0 + gb.x)));
        gbt[tk] = 1.f / (1.f + __expf(-(g1 + gb.y)));
        pa[tk] = p0; pb[tk] = p1;
    }

    // h2 = h1 @ lin_w + lin_b  (shfl-broadcast, 4 tokens jointly)
    float h2a[4] = {lb.x, lb.x, lb.x, lb.x};
    float h2b[4] = {lb.y, lb.y, lb.y, lb.y};
#pragma unroll 2
    for (int v = 0; v < U_DIM; v += 2) {
        unsigned lwA = lin_lds[v * 64 + lane];
        unsigned lwB = lin_lds[(v + 1) * 64 + lane];
        float wAx = bflo(lwA), wAy = bfhi(lwA);
        float wBx = bflo(lwB), wBy = bfhi(lwB);
        const int src = v >> 1;
#pragma unroll
        for (int tk = 0; tk < 4; ++tk) {
            float hvA = __shfl(h1a[tk], src);
            float hvB = __shfl(h1b[tk], src);
            h2a[tk] = fmaf(hvA, wAx, fmaf(hvB, wBx, h2a[tk]));
            h2b[tk] = fmaf(hvA, wAy, fmaf(hvB, wBy, h2b[tk]));
        }
    }

    // gate/residual + LayerNorm -> y pairs
    float ya[4], yb[4];
#pragma unroll
    for (int tk = 0; tk < 4; ++tk) {
        float h0 = ga[tk] * h2a[tk] + pa[tk];
        float h1 = gbt[tk] * h2b[tk] + pb[tk];
        float sum = h0 + h1;
#pragma unroll
        for (int off = 32; off; off >>= 1) sum += __shfl_xor(sum, off);
        float mu = sum * (1.0f / 128.0f);
        float d0 = h0 - mu, d1 = h1 - mu;
        float vq = d0 * d0 + d1 * d1;
#pragma unroll
        for (int off = 32; off; off >>= 1) vq += __shfl_xor(vq, off);
        float rstd = rsqrtf(vq * (1.0f / 128.0f) + 1e-3f);
        ya[tk] = d0 * rstd * lg2.x + lnb.x;
        yb[tk] = d1 * rstd * lg2.y + lnb.y;
    }

    // logits = y @ sm_w + sm_b  (lane = feature f)
    float lgt[4] = {smb, smb, smb, smb};
#pragma unroll 2
    for (int u = 0; u < U_DIM; u += 2) {
        float swA = smw_lds[u * F_DIM + lane];
        float swB = smw_lds[(u + 1) * F_DIM + lane];
        const int src = u >> 1;
#pragma unroll
        for (int tk = 0; tk < 4; ++tk) {
            float yvA = __shfl(ya[tk], src);
            float yvB = __shfl(yb[tk], src);
            lgt[tk] = fmaf(yvA, swA, fmaf(yvB, swB, lgt[tk]));
        }
    }

    // softmax over 64 lanes + outputs
#pragma unroll
    for (int tk = 0; tk < 4; ++tk) {
        const int tok = tokb + tk;
        float mx = lgt[tk];
#pragma unroll
        for (int off = 32; off; off >>= 1) mx = fmaxf(mx, __shfl_xor(mx, off));
        float ex = __expf(lgt[tk] - mx);
        float se = ex;
#pragma unroll
        for (int off = 32; off; off >>= 1) se += __shfl_xor(se, off);
        float wgt = ex / se;
        float xv = x[(size_t)tok * F_DIM + lane];
        out[(size_t)tok * F_DIM + lane] = xv * wgt;
        out[(size_t)TOK * F_DIM + (size_t)tok * F_DIM + lane] = wgt;
    }
}

// ---------------------------------------------------------------------------
extern "C" void kernel_launch(void* const* d_in, const int* in_sizes, int n_in,
                              void* d_out, int out_size, void* d_ws, size_t ws_size,
                              hipStream_t stream)
{
    const float* x      = (const float*)d_in[0];
    const float* fw     = (const float*)d_in[1];
    const float* fb     = (const float*)d_in[2];
    const float* elu_w  = (const float*)d_in[3];
    const float* elu_b  = (const float*)d_in[4];
    const float* lin_w  = (const float*)d_in[5];
    const float* lin_b  = (const float*)d_in[6];
    const float* gate_w = (const float*)d_in[7];
    const float* gate_b = (const float*)d_in[8];
    const float* proj_w = (const float*)d_in[9];
    const float* ln_g   = (const float*)d_in[10];
    const float* ln_b   = (const float*)d_in[11];
    const float* sm_w   = (const float*)d_in[12];
    const float* sm_b   = (const float*)d_in[13];

    // ws: Bp 6.29 MB | Hp (4 x bf16 partials) 25.17 MB | linp 32 KB
    char* wsb = (char*)d_ws;
    __bf16*   Bp   = (__bf16*)wsb;
    __bf16*   Hp   = (__bf16*)(wsb + (size_t)N3 * KDIM * sizeof(__bf16));
    unsigned* linp = (unsigned*)(wsb + (size_t)N3 * KDIM * sizeof(__bf16)
                                     + (size_t)KSPL * TOK * N3 * sizeof(__bf16));

    vsn_prep6<<<3 * (KDIM / 32) + 1, 256, 0, stream>>>(elu_w, gate_w, proj_w,
                                                       lin_w, Bp, linp);
    vsn_gemm6<<<dim3(KSPL, TOK / BM), 256, 0, stream>>>(x, fw, fb, Bp, Hp);
    vsn_epi6<<<TOK / 16, 256, 0, stream>>>(x, Hp, linp, elu_b, lin_b, gate_b,
                                           ln_g, ln_b, sm_w, sm_b, (float*)d_out);
}

// Round 7
// 106.099 us; speedup vs baseline: 1.3649x; 1.3649x over previous
//
#include <hip/hip_runtime.h>
#include <hip/hip_bf16.h>
#include <math.h>

// Problem dims
#define TOK   8192
#define KDIM  8192
#define F_DIM 64
#define U_DIM 128
#define N3    384

// GEMM tiling
#define BM    128
#define BK    64
#define KSPL  4
#define KRANGE (KDIM / KSPL)     // 2048
#define NST   (KRANGE / BK)      // 32
#define NF    (KRANGE / U_DIM)   // 16
#define ASTR  72
#define BSTEP_ELEM (N3 * BK)     // 24576 bf16 = 48 KB
#define BSTEP_BYTES (BSTEP_ELEM * 2)

typedef __bf16 bf16x8 __attribute__((ext_vector_type(8)));
typedef float  f32x4  __attribute__((ext_vector_type(4)));

// lgkmcnt-only barrier: LDS ops drained, global/gload_lds stay in flight
#define WG_SYNC() do {                                       \
    asm volatile("s_waitcnt lgkmcnt(0)" ::: "memory");       \
    __builtin_amdgcn_s_barrier();                            \
    __builtin_amdgcn_sched_barrier(0);                       \
} while (0)

// tanh-approx GELU: z - z/(1 + 2^(z*(2.30234 + 0.102955 z^2))), |err| < ~1e-3
__device__ __forceinline__ float gelu_fast(float z) {
    float t = z * z;
    float s = fmaf(0.1029551f, t, 2.3023457f);
    float e = __builtin_amdgcn_exp2f(z * s);
    float r = __builtin_amdgcn_rcpf(e + 1.0f);   // +inf -> 0
    return fmaf(-z, r, z);
}

__device__ __forceinline__ float bflo(unsigned u) { u <<= 16; return __builtin_bit_cast(float, u); }
__device__ __forceinline__ float bfhi(unsigned u) { u &= 0xffff0000u; return __builtin_bit_cast(float, u); }

// async global->LDS, 16B per lane: dest = wave-uniform base + lane*16,
// src = per-lane address (we pass chunk base; lane offset added here)
__device__ __forceinline__ void gload16(const void* g, void* l, int lane) {
    __builtin_amdgcn_global_load_lds(
        (const __attribute__((address_space(1))) unsigned int*)((const char*)g + lane * 16),
        (__attribute__((address_space(3))) unsigned int*)l, 16, 0, 0);
}

// ---------------------------------------------------------------------------
// Kernel 1: pack W[k][n] f32 (3 mats) into the GEMM's LDS image:
// Bp[(s*32+st)*24576 + ((ksi*4 + p)*384 + n)*8 + j], where
// k = s*2048 + st*64 + ksi*32 + p*8 + j, n = mat*128 + u.
// A linear 48KB copy of one step-tile then lands ds_read-conflict-free.
// Block 768 packs lin_w -> bf16-pair linp[128][64].
// ---------------------------------------------------------------------------
__global__ __launch_bounds__(256) void vsn_prep7(
    const float* __restrict__ elu_w,
    const float* __restrict__ gate_w,
    const float* __restrict__ proj_w,
    const float* __restrict__ lin_w,
    __bf16* __restrict__ Bp,
    unsigned* __restrict__ linp)
{
    const int t = threadIdx.x;
    if (blockIdx.x == 3 * (KDIM / 32)) {
#pragma unroll
        for (int i = 0; i < 32; ++i) {
            int idx = i * 256 + t;            // 0..8191
            int v = idx >> 6, l = idx & 63;
            __bf16 ba = (__bf16)lin_w[v * U_DIM + 2 * l];
            __bf16 bb = (__bf16)lin_w[v * U_DIM + 2 * l + 1];
            unsigned pa = (unsigned)__builtin_bit_cast(unsigned short, ba);
            unsigned pb = (unsigned)__builtin_bit_cast(unsigned short, bb);
            linp[idx] = pa | (pb << 16);
        }
        return;
    }
    __shared__ float tile[32][U_DIM + 1];
    const int mat = blockIdx.x / (KDIM / 32);   // 0..2
    const int kb  = blockIdx.x % (KDIM / 32);   // 0..255 (32 k-rows each)
    const float* W = (mat == 0) ? elu_w : (mat == 1 ? gate_w : proj_w);

#pragma unroll
    for (int i = 0; i < 16; ++i) {
        int idx = i * 256 + t;
        int r = idx >> 7, c = idx & 127;
        tile[r][c] = W[(size_t)(kb * 32 + r) * U_DIM + c];
    }
    __syncthreads();

    const int s   = kb >> 6;           // k-split
    const int st  = (kb & 63) >> 1;    // K-step within split
    const int ksi = kb & 1;            // 32-k half
    __bf16* dstb = Bp + (size_t)(s * NST + st) * BSTEP_ELEM
                      + (size_t)ksi * 4 * 384 * 8;
#pragma unroll
    for (int i = 0; i < 2; ++i) {
        int idx = i * 256 + t;         // 0..511 = 4 planes x 128 u
        int p = idx >> 7, u = idx & 127;
        bf16x8 v;
#pragma unroll
        for (int j = 0; j < 8; ++j)
            v[j] = (__bf16)tile[p * 8 + j][u];
        *(bf16x8*)&dstb[((size_t)p * 384 + mat * U_DIM + u) * 8] = v;
    }
}

// ---------------------------------------------------------------------------
// Kernel 2: fused gelu-feat + 3-way GEMM, BM=128, LDS-staged B (unique
// bytes only through L2). grid = (KSPL=4, 64) = 256 WGs (1/CU), 512 thr
// (8 waves = 2m x 4n), acc[4][6]. Double-buffered A (gelu, 1x) and B
// (global_load_lds). One lgkmcnt-barrier per step; vmcnt(0) at step end
// (stage issued a full step ahead). XCD id%8 in {s, s+4}: split-local L2.
// ---------------------------------------------------------------------------
__global__ __launch_bounds__(512, 2) void vsn_gemm7(
    const float* __restrict__ x,
    const float* __restrict__ fw,
    const float* __restrict__ fb,
    const __bf16* __restrict__ Bp,
    __bf16* __restrict__ Hp)
{
    __shared__ __bf16 b_lds[2][BSTEP_ELEM];   // 96 KB
    __shared__ __bf16 a_lds[2][BM][ASTR];     // 36.9 KB
    __shared__ float  x_lds[BM][NF + 1];      // 8.7 KB
    __shared__ __bf16 fw_lds[KRANGE];         // 4 KB
    __shared__ __bf16 fb_lds[KRANGE];         // 4 KB

    const int t    = threadIdx.x;
    const int wave = t >> 6;
    const int lane = t & 63;
    const int s     = blockIdx.x;
    const int tok0  = blockIdx.y * BM;
    const int kbase = s * KRANGE;
    const int wm = wave >> 2;                 // 0..1 : 64-row band
    const int wn = wave & 3;                  // 0..3 : 96-col band
    const int lr  = lane & 15;
    const int pl  = lane >> 4;                // k-plane 0..3
    const int lk8 = pl * 8;

    // ---- stage x (128x16), fw/fb (2048 each)
#pragma unroll
    for (int i = 0; i < 4; ++i) {
        int idx = i * 512 + t;
        x_lds[idx >> 4][idx & 15] = x[(size_t)(tok0 + (idx >> 4)) * F_DIM
                                      + (kbase >> 7) + (idx & 15)];
        fw_lds[idx] = (__bf16)fw[kbase + idx];
        fb_lds[idx] = (__bf16)fb[kbase + idx];
    }

    f32x4 acc[4][6];
#pragma unroll
    for (int i = 0; i < 4; ++i)
#pragma unroll
        for (int j = 0; j < 6; ++j)
            acc[i][j] = (f32x4){0.f, 0.f, 0.f, 0.f};

    const int m_a = t >> 2;          // 0..127: A row this thread computes
    const int kk  = (t & 3) * 16;    // 0..48 : A k-subcol (16 elems)

    auto gelu_write = [&](int st, int buf) {
        const int k0 = st * BK;
        const float xs = x_lds[m_a][(k0 + kk) >> 7];
#pragma unroll
        for (int h = 0; h < 2; ++h) {
            bf16x8 wv = *(const bf16x8*)&fw_lds[k0 + kk + h * 8];
            bf16x8 bv = *(const bf16x8*)&fb_lds[k0 + kk + h * 8];
            bf16x8 av;
#pragma unroll
            for (int j = 0; j < 8; ++j) {
                float z = fmaf(xs, (float)wv[j], (float)bv[j]);
                av[j] = (__bf16)gelu_fast(z);
            }
            *(bf16x8*)&a_lds[buf][m_a][kk + h * 8] = av;
        }
    };

    // B stage: 48 chunks of 1KB per step; wave w copies chunks [6w, 6w+6)
    const char* bsrc = (const char*)Bp + (size_t)(s * NST) * BSTEP_BYTES
                                       + (size_t)wave * 6 * 1024;
    auto stageB = [&](int st, int buf) {
        const char* src = bsrc + (size_t)st * BSTEP_BYTES;
        char* dst = (char*)&b_lds[buf][0] + wave * 6 * 1024;
#pragma unroll
        for (int c = 0; c < 6; ++c)
            gload16(src + c * 1024, dst + c * 1024, lane);
    };

    stageB(0, 0);
    asm volatile("s_waitcnt vmcnt(0) lgkmcnt(0)" ::: "memory");
    __builtin_amdgcn_s_barrier();
    __builtin_amdgcn_sched_barrier(0);
    gelu_write(0, 0);                 // a0 (visible after loop-top barrier)

    for (int st = 0; st < NST; ++st) {
        const int cur = st & 1;
        WG_SYNC();                    // a[cur],b[cur] visible; [cur^1] free

        if (st + 1 < NST) {
            stageB(st + 1, cur ^ 1);      // async, rides across the step
            gelu_write(st + 1, cur ^ 1);  // VALU hides stage latency
        }

#pragma unroll
        for (int ksi = 0; ksi < 2; ++ksi) {
            bf16x8 bf[6];
#pragma unroll
            for (int j = 0; j < 6; ++j)
                bf[j] = *(const bf16x8*)
                    &b_lds[cur][(((ksi * 4 + pl) * 384) + wn * 96 + j * 16 + lr) * 8];
            bf16x8 af[4];
#pragma unroll
            for (int i = 0; i < 4; ++i)
                af[i] = *(const bf16x8*)
                    &a_lds[cur][wm * 64 + i * 16 + lr][ksi * 32 + lk8];

            __builtin_amdgcn_s_setprio(1);
#pragma unroll
            for (int i = 0; i < 4; ++i)
#pragma unroll
                for (int j = 0; j < 6; ++j)
                    acc[i][j] = __builtin_amdgcn_mfma_f32_16x16x32_bf16(
                        af[i], bf[j], acc[i][j], 0, 0, 0);
            __builtin_amdgcn_s_setprio(0);
        }

        if (st + 1 < NST)
            asm volatile("s_waitcnt vmcnt(0)" ::: "memory");  // b[nxt] landed
    }

    // ---- write bf16 partials (C/D: col=lane&15, row=(lane>>4)*4+r)
    __bf16* Hs = Hp + (size_t)s * ((size_t)TOK * N3);
    const int r0 = (lane >> 4) * 4;
#pragma unroll
    for (int i = 0; i < 4; ++i)
#pragma unroll
        for (int j = 0; j < 6; ++j)
#pragma unroll
            for (int r = 0; r < 4; ++r)
                Hs[(size_t)(tok0 + wm * 64 + i * 16 + r0 + r) * N3
                   + wn * 96 + j * 16 + lr] = (__bf16)acc[i][j][r];
}

// ---------------------------------------------------------------------------
// Kernel 3: epilogue. grid = TOK/16 = 512 WGs x 256 thr; wave = 4 tokens.
// Lane l owns feature pair (2l, 2l+1); shfl-broadcast matmuls over 4 tokens.
// ---------------------------------------------------------------------------
__global__ __launch_bounds__(256) void vsn_epi7(
    const float* __restrict__ x,
    const __bf16* __restrict__ Hp,
    const unsigned* __restrict__ linp,
    const float* __restrict__ elu_b,
    const float* __restrict__ lin_b,
    const float* __restrict__ gate_b,
    const float* __restrict__ ln_g,
    const float* __restrict__ ln_b,
    const float* __restrict__ sm_w,
    const float* __restrict__ sm_b,
    float* __restrict__ out)
{
    __shared__ unsigned lin_lds[U_DIM * 64];     // 32 KB (bf16 pairs)
    __shared__ float    smw_lds[U_DIM * F_DIM];  // 32 KB
    const int t = threadIdx.x, wave = t >> 6, lane = t & 63;
    const int tokb = blockIdx.x * 16 + wave * 4;

    {
        const uint4* l4 = (const uint4*)linp;
        uint4* d4 = (uint4*)lin_lds;
#pragma unroll
        for (int i = 0; i < 8; ++i) d4[i * 256 + t] = l4[i * 256 + t];
        const f32x4* s4 = (const f32x4*)sm_w;
        f32x4* m4 = (f32x4*)smw_lds;
#pragma unroll
        for (int i = 0; i < 8; ++i) m4[i * 256 + t] = s4[i * 256 + t];
    }
    __syncthreads();

    const float2 eb  = *(const float2*)&elu_b[2 * lane];
    const float2 gb  = *(const float2*)&gate_b[2 * lane];
    const float2 lb  = *(const float2*)&lin_b[2 * lane];
    const float2 lg2 = *(const float2*)&ln_g[2 * lane];
    const float2 lnb = *(const float2*)&ln_b[2 * lane];
    const float  smb = sm_b[lane];

    float h1a[4], h1b[4], ga[4], gbt[4], pa[4], pb[4];
#pragma unroll
    for (int tk = 0; tk < 4; ++tk) {
        const unsigned short* base =
            (const unsigned short*)Hp + (size_t)(tokb + tk) * N3;
        float a0 = 0.f, a1 = 0.f, g0 = 0.f, g1 = 0.f, p0 = 0.f, p1 = 0.f;
#pragma unroll
        for (int s = 0; s < KSPL; ++s) {
            const unsigned short* bs = base + (size_t)s * TOK * N3;
            unsigned ua = *(const unsigned*)(bs + 2 * lane);
            unsigned ug = *(const unsigned*)(bs + 128 + 2 * lane);
            unsigned up = *(const unsigned*)(bs + 256 + 2 * lane);
            a0 += bflo(ua); a1 += bfhi(ua);
            g0 += bflo(ug); g1 += bfhi(ug);
            p0 += bflo(up); p1 += bfhi(up);
        }
        float e0 = a0 + eb.x, e1 = a1 + eb.y;
        h1a[tk] = (e0 > 0.f) ? e0 : expm1f(e0);
        h1b[tk] = (e1 > 0.f) ? e1 : expm1f(e1);
        ga[tk]  = 1.f / (1.f + __expf(-(g0 + gb.x)));
        gbt[tk] = 1.f / (1.f + __expf(-(g1 + gb.y)));
        pa[tk] = p0; pb[tk] = p1;
    }

    // h2 = h1 @ lin_w + lin_b  (shfl-broadcast, 4 tokens jointly)
    float h2a[4] = {lb.x, lb.x, lb.x, lb.x};
    float h2b[4] = {lb.y, lb.y, lb.y, lb.y};
#pragma unroll 2
    for (int v = 0; v < U_DIM; v += 2) {
        unsigned lwA = lin_lds[v * 64 + lane];
        unsigned lwB = lin_lds[(v + 1) * 64 + lane];
        float wAx = bflo(lwA), wAy = bfhi(lwA);
        float wBx = bflo(lwB), wBy = bfhi(lwB);
        const int src = v >> 1;
#pragma unroll
        for (int tk = 0; tk < 4; ++tk) {
            float hvA = __shfl(h1a[tk], src);
            float hvB = __shfl(h1b[tk], src);
            h2a[tk] = fmaf(hvA, wAx, fmaf(hvB, wBx, h2a[tk]));
            h2b[tk] = fmaf(hvA, wAy, fmaf(hvB, wBy, h2b[tk]));
        }
    }

    // gate/residual + LayerNorm -> y pairs
    float ya[4], yb[4];
#pragma unroll
    for (int tk = 0; tk < 4; ++tk) {
        float h0 = ga[tk] * h2a[tk] + pa[tk];
        float h1 = gbt[tk] * h2b[tk] + pb[tk];
        float sum = h0 + h1;
#pragma unroll
        for (int off = 32; off; off >>= 1) sum += __shfl_xor(sum, off);
        float mu = sum * (1.0f / 128.0f);
        float d0 = h0 - mu, d1 = h1 - mu;
        float vq = d0 * d0 + d1 * d1;
#pragma unroll
        for (int off = 32; off; off >>= 1) vq += __shfl_xor(vq, off);
        float rstd = rsqrtf(vq * (1.0f / 128.0f) + 1e-3f);
        ya[tk] = d0 * rstd * lg2.x + lnb.x;
        yb[tk] = d1 * rstd * lg2.y + lnb.y;
    }

    // logits = y @ sm_w + sm_b  (lane = feature f)
    float lgt[4] = {smb, smb, smb, smb};
#pragma unroll 2
    for (int u = 0; u < U_DIM; u += 2) {
        float swA = smw_lds[u * F_DIM + lane];
        float swB = smw_lds[(u + 1) * F_DIM + lane];
        const int src = u >> 1;
#pragma unroll
        for (int tk = 0; tk < 4; ++tk) {
            float yvA = __shfl(ya[tk], src);
            float yvB = __shfl(yb[tk], src);
            lgt[tk] = fmaf(yvA, swA, fmaf(yvB, swB, lgt[tk]));
        }
    }

    // softmax over 64 lanes + outputs
#pragma unroll
    for (int tk = 0; tk < 4; ++tk) {
        const int tok = tokb + tk;
        float mx = lgt[tk];
#pragma unroll
        for (int off = 32; off; off >>= 1) mx = fmaxf(mx, __shfl_xor(mx, off));
        float ex = __expf(lgt[tk] - mx);
        float se = ex;
#pragma unroll
        for (int off = 32; off; off >>= 1) se += __shfl_xor(se, off);
        float wgt = ex / se;
        float xv = x[(size_t)tok * F_DIM + lane];
        out[(size_t)tok * F_DIM + lane] = xv * wgt;
        out[(size_t)TOK * F_DIM + (size_t)tok * F_DIM + lane] = wgt;
    }
}

// ---------------------------------------------------------------------------
extern "C" void kernel_launch(void* const* d_in, const int* in_sizes, int n_in,
                              void* d_out, int out_size, void* d_ws, size_t ws_size,
                              hipStream_t stream)
{
    const float* x      = (const float*)d_in[0];
    const float* fw     = (const float*)d_in[1];
    const float* fb     = (const float*)d_in[2];
    const float* elu_w  = (const float*)d_in[3];
    const float* elu_b  = (const float*)d_in[4];
    const float* lin_w  = (const float*)d_in[5];
    const float* lin_b  = (const float*)d_in[6];
    const float* gate_w = (const float*)d_in[7];
    const float* gate_b = (const float*)d_in[8];
    const float* proj_w = (const float*)d_in[9];
    const float* ln_g   = (const float*)d_in[10];
    const float* ln_b   = (const float*)d_in[11];
    const float* sm_w   = (const float*)d_in[12];
    const float* sm_b   = (const float*)d_in[13];

    // ws: Bp 6.29 MB | Hp (4 x bf16 partials) 25.17 MB | linp 32 KB
    char* wsb = (char*)d_ws;
    __bf16*   Bp   = (__bf16*)wsb;
    __bf16*   Hp   = (__bf16*)(wsb + (size_t)N3 * KDIM * sizeof(__bf16));
    unsigned* linp = (unsigned*)(wsb + (size_t)N3 * KDIM * sizeof(__bf16)
                                     + (size_t)KSPL * TOK * N3 * sizeof(__bf16));

    vsn_prep7<<<3 * (KDIM / 32) + 1, 256, 0, stream>>>(elu_w, gate_w, proj_w,
                                                       lin_w, Bp, linp);
    vsn_gemm7<<<dim3(KSPL, TOK / BM), 512, 0, stream>>>(x, fw, fb, Bp, Hp);
    vsn_epi7<<<TOK / 16, 256, 0, stream>>>(x, Hp, linp, elu_b, lin_b, gate_b,
                                           ln_g, ln_b, sm_w, sm_b, (float*)d_out);
}